// Round 8
// baseline (109.236 us; speedup 1.0000x reference)
//
#include <hip/hip_runtime.h>
#include <hip/hip_fp16.h>

// NNUE forward, round 8: int8 embedding table with per-row fp16 scales.
// Gather theory: fp16 rows = 256 B = 2 cache lines; measured 45 cyc/wave-load
// = ~5.6 cyc/line-fill (L1 miss processing is the bind; occupancy & ILP both
// proven neutral in R4/R5). int8 rows = 128 B = ONE line -> line-fills halve.
// Dequant via fp16-denormal trick: byte u in low byte of an fp16 half is
// exactly u*2^-24; v_perm builds a pair, pk_add(-128*2^-24) recenters (exact
// in denormal space), pk_fma with s' = s*2^24 accumulates. 3 VALU / 2 dims.
// Phase 2 (dot2 dense layers) unchanged from round 7.

#define STR2 33

using h2  = _Float16 __attribute__((ext_vector_type(2)));

union HU { unsigned u; h2 h; };

__device__ __forceinline__ float frelu(float v) { return v > 0.f ? v : 0.f; }

// ---- staging: quantize emb to int8 + per-row scale; last block packs weights ----
__global__ __launch_bounds__(256) void stage_q(
    const float* __restrict__ emb, unsigned char* __restrict__ tab8,
    _Float16* __restrict__ sc16,
    const float* __restrict__ w2, const float* __restrict__ w3,
    const float* __restrict__ w4,
    _Float16* __restrict__ w2p, h2* __restrict__ w3p, h2* __restrict__ w4p)
{
    if ((int)blockIdx.x == (int)gridDim.x - 1) {
        const int i = threadIdx.x;
        for (int e = i; e < 32 * 128; e += 256) w2p[e] = (_Float16)w2[e];
        for (int p = i; p < 32 * 32; p += 256) {
            const int o = p >> 5, j = p & 31;
            h2 c; c[0] = (_Float16)w3[o * 64 + j];
            c[1] = (_Float16)w3[o * 64 + 32 + j];
            w3p[p] = c;
        }
        if (i < 32) {
            h2 c; c[0] = (_Float16)w4[i]; c[1] = (_Float16)w4[32 + i];
            w4p[i] = c;
        }
        return;
    }
    const int t = threadIdx.x, lane = t & 63, wave = t >> 6;
    const int row = blockIdx.x * 4 + wave;                 // 4 rows/block
    const float2 e = ((const float2*)(emb + (size_t)row * 128))[lane];
    float m = fmaxf(fabsf(e.x), fabsf(e.y));
    #pragma unroll
    for (int off = 32; off >= 1; off >>= 1)
        m = fmaxf(m, __shfl_xor(m, off, 64));
    const float s = fmaxf(m, 1e-8f) * (1.0f / 127.0f);
    const _Float16 s16 = (_Float16)(s * 16777216.0f);      // s * 2^24 (fp16)
    const float s_used = (float)s16 * 5.9604644775390625e-8f;  // back to s
    const float inv = 1.0f / s_used;
    int q0 = (int)rintf(e.x * inv); q0 = q0 > 127 ? 127 : (q0 < -127 ? -127 : q0);
    int q1 = (int)rintf(e.y * inv); q1 = q1 > 127 ? 127 : (q1 < -127 ? -127 : q1);
    uchar2 pk; pk.x = (unsigned char)(q0 + 128); pk.y = (unsigned char)(q1 + 128);
    ((uchar2*)(tab8 + (size_t)row * 128))[lane] = pk;
    if (lane == 0) sc16[row] = s16;
}

__global__ __launch_bounds__(256, 4) void nnue_fwd(
    const int* __restrict__ x, const unsigned char* __restrict__ tab8,
    const _Float16* __restrict__ sc16,
    const h2* __restrict__ w2p, const float* __restrict__ b2,
    const h2* __restrict__ w3p, const float* __restrict__ b3,
    const h2* __restrict__ w4p, float* __restrict__ out)
{
    __shared__ h2 lds[64 * STR2];   // 8448 B

    const int t    = threadIdx.x;
    const int lane = t & 63;
    const int grp  = lane >> 3;        // which of 8 rows this wave-load
    const int sub  = lane & 7;         // 16-byte (16-dim) chunk within a row
    const int row0 = blockIdx.x * 32;
    const int wave = __builtin_amdgcn_readfirstlane(t >> 6);

    // ---------------- Phase 1: int8 gather + denormal-trick dequant ----------------
    // wave handles rows [wave*8, wave*8+8) in ONE pass of 29 wave-loads.
    const size_t xbase = (size_t)(row0 + wave * 8 + grp) * 32;
    int xq[4];
    #pragma unroll
    for (int q = 0; q < 4; ++q)
        xq[q] = __builtin_nontemporal_load(x + xbase + sub + 8 * q);

    HU cn; cn.u = 0x80808080u;         // pair (-128*2^-24, -128*2^-24)
    const h2 cneg = cn.h;

    h2 accA[8] = {}, accB[8] = {};
    #pragma unroll
    for (int j = 0; j < 29; ++j) {
        const int idx = __shfl(xq[j >> 3], (lane & 56) | (j & 7), 64);
        const uint4 d = *(const uint4*)(tab8 + ((size_t)(unsigned)idx << 7)
                                             + (sub << 4));
        const _Float16 sv = sc16[idx];          // 30 KB table: L1-resident
        h2 sp; sp[0] = sv; sp[1] = sv;
        #pragma unroll
        for (int w = 0; w < 4; ++w) {
            const unsigned dw = (&d.x)[w];
            HU a, b;
            a.u = __builtin_amdgcn_perm(0u, dw, 0x04010400u); // (u1,u0)*2^-24
            b.u = __builtin_amdgcn_perm(0u, dw, 0x04030402u); // (u3,u2)*2^-24
            const h2 p0 = a.h + cneg;           // q*2^-24, exact
            const h2 p1 = b.h + cneg;
            if (j & 1) { accB[2*w] += p0 * sp; accB[2*w+1] += p1 * sp; }
            else       { accA[2*w] += p0 * sp; accA[2*w+1] += p1 * sp; }
        }
    }
    #pragma unroll
    for (int k = 0; k < 8; ++k) {
        h2 s = accA[k] + accB[k];
        s[0] = s[0] > (_Float16)0 ? s[0] : (_Float16)0;
        s[1] = s[1] > (_Float16)0 ? s[1] : (_Float16)0;
        lds[(8 * sub + k) * STR2 + wave * 8 + grp] = s;  // [pair-dim][row]
    }
    __syncthreads();

    // ---------------- Phase 2: dense layers (identical to round 7) ----------------
    const int r  = lane & 31;
    const int hf = lane >> 5;
    const int ob = __builtin_amdgcn_readfirstlane((t >> 6) * 8); // 8 outs/wave

    float a2[8];
    #pragma unroll
    for (int oo = 0; oo < 8; ++oo) a2[oo] = b2[ob + oo];
    #pragma unroll 8
    for (int pd = 0; pd < 64; ++pd) {
        const h2 hp = lds[pd * STR2 + r];
        #pragma unroll
        for (int oo = 0; oo < 8; ++oo)
            a2[oo] = __builtin_amdgcn_fdot2(hp, w2p[(ob + oo) * 64 + pd],
                                            a2[oo], false);
    }
    __syncthreads();
    if (hf == 0) {
        #pragma unroll
        for (int oo = 0; oo < 8; ++oo) {
            h2 c; c[0] = (_Float16)frelu(a2[oo]); c[1] = (_Float16)frelu(-a2[oo]);
            lds[(ob + oo) * STR2 + r] = c;           // c2: pd rows 0..31
        }
    }
    __syncthreads();

    float a3[8];
    #pragma unroll
    for (int oo = 0; oo < 8; ++oo) a3[oo] = b3[ob + oo];
    #pragma unroll 8
    for (int j = 0; j < 32; ++j) {
        const h2 cp = lds[j * STR2 + r];
        #pragma unroll
        for (int oo = 0; oo < 8; ++oo)
            a3[oo] = __builtin_amdgcn_fdot2(cp, w3p[(ob + oo) * 32 + j],
                                            a3[oo], false);
    }
    if (hf == 0) {
        #pragma unroll
        for (int oo = 0; oo < 8; ++oo) {
            h2 c; c[0] = (_Float16)frelu(a3[oo]); c[1] = (_Float16)frelu(-a3[oo]);
            lds[(32 + ob + oo) * STR2 + r] = c;      // c3: pd rows 32..63
        }
    }
    __syncthreads();

    if (t < 32) {
        float s = 0.f;
        #pragma unroll
        for (int j = 0; j < 32; ++j)
            s = __builtin_amdgcn_fdot2(lds[(32 + j) * STR2 + t], w4p[j], s, false);
        __builtin_nontemporal_store(s, out + row0 + t);
    }
}

extern "C" void kernel_launch(void* const* d_in, const int* in_sizes, int n_in,
                              void* d_out, int out_size, void* d_ws, size_t ws_size,
                              hipStream_t stream) {
    const int*   x   = (const int*)d_in[0];
    const float* emb = (const float*)d_in[1];
    const float* w2  = (const float*)d_in[2];
    const float* b2  = (const float*)d_in[3];
    const float* w3  = (const float*)d_in[4];
    const float* b3  = (const float*)d_in[5];
    const float* w4  = (const float*)d_in[6];
    float* out = (float*)d_out;

    const int n_rows = in_sizes[0] / 32;        // 65536
    const int vocab  = in_sizes[1] / 128;       // 14848

    char* ws = (char*)d_ws;
    unsigned char* tab8 = (unsigned char*)ws;            // 1,900,544 B (128-aligned)
    _Float16* sc16 = (_Float16*)(ws + 1900544);          // 29,696 B
    _Float16* w2p  = (_Float16*)(ws + 1930240);          // 8,192 B
    h2*       w3p  = (h2*)(ws + 1938432);                // 4,096 B
    h2*       w4p  = (h2*)(ws + 1942528);                // 128 B

    hipLaunchKernelGGL(stage_q, dim3(vocab / 4 + 1), dim3(256), 0, stream,
                       emb, tab8, sc16, w2, w3, w4, w2p, w3p, w4p);
    hipLaunchKernelGGL(nnue_fwd, dim3(n_rows / 32), dim3(256), 0, stream,
                       x, tab8, sc16, (const h2*)w2p, b2, w3p, b3, w4p, out);
}